// Round 1
// baseline (435.160 us; speedup 1.0000x reference)
//
#include <hip/hip_runtime.h>
#include <math.h>

#define NN 500000
#define Q 64
#define NPB 256   // nodes per block

__device__ __forceinline__ float fast_tanh(float x) {
    // tanh(x) = 1 - 2/(exp(2x)+1); exact limits at +-inf
    float e = __expf(2.0f * x);
    return 1.0f - __fdividef(2.0f, e + 1.0f);
}

__global__ __launch_bounds__(256)
void bgk_fused(const float* __restrict__ f,
               const float* __restrict__ macro,
               const float* __restrict__ pos,
               const float* __restrict__ W0, const float* __restrict__ b0,
               const float* __restrict__ W1, const float* __restrict__ b1,
               const float* __restrict__ W2, const float* __restrict__ b2,
               const float* __restrict__ W3, const float* __restrict__ b3,
               const float* __restrict__ W4, const float* __restrict__ b4,
               float* __restrict__ out, int n_nodes) {
    __shared__ float s_lam[NPB];
    __shared__ float s_mu0[NPB];
    __shared__ float s_it[NPB];

    const float XI_H = 70.0f / 63.0f;          // grid step h
    const int tid = threadIdx.x;
    const long long nbase = (long long)blockIdx.x * NPB;
    const long long n1 = nbase + tid;

    // ---------------- Phase 1: per-node MLP + analytic lambda solve ----------------
    if (n1 < n_nodes) {
        const float m0 = macro[n1 * 2 + 0];
        const float m1 = macro[n1 * 2 + 1];
        const float pp = pos[n1];

        float h[64];
        // layer 0: 3 -> 64
        #pragma unroll
        for (int i = 0; i < 64; ++i) {
            float acc = b0[i];
            acc = fmaf(W0[i * 3 + 0], m0, acc);
            acc = fmaf(W0[i * 3 + 1], m1, acc);
            acc = fmaf(W0[i * 3 + 2], pp, acc);
            h[i] = fast_tanh(acc);
        }
        // layers 1..3: 64 -> 64 (looped to keep code size down)
        #pragma unroll 1
        for (int l = 0; l < 3; ++l) {
            const float* Wl;
            const float* bl;
            if (l == 0)      { Wl = W1; bl = b1; }
            else if (l == 1) { Wl = W2; bl = b2; }
            else             { Wl = W3; bl = b3; }
            float hn[64];
            #pragma unroll
            for (int i = 0; i < 64; ++i) {
                float acc = bl[i];
                #pragma unroll
                for (int j = 0; j < 64; ++j)
                    acc = fmaf(Wl[i * 64 + j], h[j], acc);
                hn[i] = acc;
            }
            #pragma unroll
            for (int i = 0; i < 64; ++i) h[i] = fast_tanh(hn[i]);
        }
        // layer 4: 64 -> 1, tau = exp(z)
        float z = b4[0];
        #pragma unroll
        for (int j = 0; j < 64; ++j) z = fmaf(W4[j], h[j], z);
        const float inv_tau = __expf(-z);

        // analytic equilibrium: lambda s.t. geometric mean == v
        const float v = m0;
        float r = v / (v + XI_H);
        r = fmaxf(r, 1e-30f);                  // guard v == 0
        const float lam = logf(r) / XI_H;
        const float r64 = __expf(64.0f * logf(r));   // ~<= 2e-21, kept for exactness
        const float S0 = (1.0f - r64) / (1.0f - r);
        const float mu0 = -logf(S0);

        s_lam[tid] = lam;
        s_mu0[tid] = mu0;
        s_it[tid]  = inv_tau;
    } else {
        s_lam[tid] = 0.0f;
        s_mu0[tid] = 0.0f;
        s_it[tid]  = 0.0f;
    }
    __syncthreads();

    // ---------------- Phase 2: wave-per-node streaming of f / omega ----------------
    const int wave = tid >> 6;
    const int lane = tid & 63;
    const float xi = (float)lane * XI_H;

    for (int k = 0; k < 64; ++k) {
        const int local = (wave << 6) + k;
        const long long n = nbase + local;
        if (n >= n_nodes) break;

        const float fv = f[n * Q + lane];

        // wave sum -> rho
        float s = fv;
        #pragma unroll
        for (int m = 1; m < 64; m <<= 1) s += __shfl_xor(s, m, 64);
        const float rho = s * (1.0f / 64.0f);

        const float lam = s_lam[local];
        const float mu0 = s_mu0[local];
        const float it  = s_it[local];

        const float feq = rho * __expf(fmaf(lam, xi, mu0));
        out[n * Q + lane] = (feq - fv) * it;
    }
}

extern "C" void kernel_launch(void* const* d_in, const int* in_sizes, int n_in,
                              void* d_out, int out_size, void* d_ws, size_t ws_size,
                              hipStream_t stream) {
    const float* f     = (const float*)d_in[0];
    const float* macro = (const float*)d_in[1];
    const float* pos   = (const float*)d_in[2];
    const float* W0 = (const float*)d_in[3];  const float* b0 = (const float*)d_in[4];
    const float* W1 = (const float*)d_in[5];  const float* b1 = (const float*)d_in[6];
    const float* W2 = (const float*)d_in[7];  const float* b2 = (const float*)d_in[8];
    const float* W3 = (const float*)d_in[9];  const float* b3 = (const float*)d_in[10];
    const float* W4 = (const float*)d_in[11]; const float* b4 = (const float*)d_in[12];
    float* out = (float*)d_out;

    const int n_nodes = in_sizes[0] / Q;   // 500000
    const int blocks = (n_nodes + NPB - 1) / NPB;

    bgk_fused<<<blocks, NPB, 0, stream>>>(f, macro, pos,
                                          W0, b0, W1, b1, W2, b2, W3, b3, W4, b4,
                                          out, n_nodes);
}

// Round 2
// 317.407 us; speedup vs baseline: 1.3710x; 1.3710x over previous
//
#include <hip/hip_runtime.h>
#include <math.h>

#define Q 64
#define NPB 256

__device__ __forceinline__ float fast_tanh(float x) {
    // tanh(x) = 1 - 2/(exp(2x)+1)
    float e = __expf(2.0f * x);
    return 1.0f - __fdividef(2.0f, e + 1.0f);
}

// Transpose W1,W2,W3 (each 64x64 row-major [out][in]) into Wt[l][in][out]
// so the main kernel can fetch weight "columns" as contiguous scalar loads.
__global__ __launch_bounds__(256)
void transpose_w(const float* __restrict__ W1, const float* __restrict__ W2,
                 const float* __restrict__ W3, float* __restrict__ Wt) {
    int idx = blockIdx.x * 256 + threadIdx.x;
    if (idx >= 3 * 4096) return;
    int l = idx >> 12, rc = idx & 4095, r = rc >> 6, c = rc & 63;
    const float* W = (l == 0) ? W1 : (l == 1) ? W2 : W3;
    Wt[(l << 12) + (c << 6) + r] = W[rc];
}

__global__ __launch_bounds__(NPB)
void bgk_fused(const float* __restrict__ f,
               const float* __restrict__ macro,
               const float* __restrict__ pos,
               const float* __restrict__ W0, const float* __restrict__ b0,
               const float* __restrict__ b1, const float* __restrict__ b2,
               const float* __restrict__ b3,
               const float* __restrict__ W4, const float* __restrict__ b4,
               const float* __restrict__ Wt,
               float* __restrict__ out, int n_nodes) {
    // Thread-private activation storage: column tid, row j. Lanes consecutive
    // -> banks consecutive -> conflict-free (2 lanes/bank is free).
    __shared__ float lds[Q * NPB];   // 64 KiB

    const int tid = threadIdx.x;
    const long long nbase = (long long)blockIdx.x * NPB;
    const long long n1 = nbase + tid;
    const long long nc = (n1 < n_nodes) ? n1 : (long long)(n_nodes - 1);

    const float m0 = macro[nc * 2 + 0];
    const float m1 = macro[nc * 2 + 1];
    const float pp = pos[nc];

    // ---------------- L0: 3 -> 64 ----------------
    #pragma unroll
    for (int i = 0; i < 64; ++i) {
        float a = b0[i];
        a = fmaf(W0[i * 3 + 0], m0, a);
        a = fmaf(W0[i * 3 + 1], m1, a);
        a = fmaf(W0[i * 3 + 2], pp, a);
        lds[i * NPB + tid] = fast_tanh(a);
    }

    float acc[64];

    // Hidden 64->64 layer: acc[i] = b[i] + sum_j Wt[j][i] * h[j]
    // j rolled (uniform -> weight row is 64 contiguous scalar loads),
    // i fully unrolled (1-FMA body -> guaranteed unroll -> acc stays in VGPRs).
#define DENSE(WTOFF, BL)                                              \
    {                                                                 \
        _Pragma("unroll")                                             \
        for (int i = 0; i < 64; ++i) acc[i] = BL[i];                  \
        for (int j = 0; j < 64; ++j) {                                \
            const float hj = lds[j * NPB + tid];                      \
            const float* __restrict__ wr = Wt + (WTOFF) + j * 64;     \
            _Pragma("unroll")                                         \
            for (int i = 0; i < 64; ++i)                              \
                acc[i] = fmaf(wr[i], hj, acc[i]);                     \
        }                                                             \
    }

    DENSE(0, b1)
    #pragma unroll
    for (int i = 0; i < 64; ++i) lds[i * NPB + tid] = fast_tanh(acc[i]);

    DENSE(4096, b2)
    #pragma unroll
    for (int i = 0; i < 64; ++i) lds[i * NPB + tid] = fast_tanh(acc[i]);

    DENSE(8192, b3)
    // L4: 64 -> 1 directly from registers
    float z = b4[0];
    #pragma unroll
    for (int i = 0; i < 64; ++i) z = fmaf(W4[i], fast_tanh(acc[i]), z);
    const float inv_tau = __expf(-z);

    // ---------------- analytic lambda/mu0 (geometric fixed point) ----------------
    const float XI_H = 70.0f / 63.0f;
    float r = m0 / (m0 + XI_H);
    r = fmaxf(r, 1e-30f);
    const float lr  = logf(r);
    const float lam = lr / XI_H;
    const float r64 = __expf(64.0f * lr);
    const float S0  = (1.0f - r64) / (1.0f - r);
    const float mu0 = -logf(S0);

    // Hand off via LDS (each thread touches only its own column; phase 2 reads
    // only values written by its own wave's lanes -> no barrier required, but
    // keep one for safety; it's once per block).
    __syncthreads();
    lds[tid]           = lam;
    lds[NPB + tid]     = mu0;
    lds[2 * NPB + tid] = inv_tau;
    __syncthreads();

    // ---------------- Phase 2: streaming omega, 4 nodes per wave-iter ----------------
    const int wv   = tid >> 6;
    const int lane = tid & 63;
    const int sub  = lane >> 4;          // node-in-group 0..3
    const int qi   = (lane & 15) * 4;    // q start, 16B aligned

    for (int k = 0; k < 16; ++k) {
        const int local = (wv << 6) + k * 4 + sub;
        const long long n = nbase + local;
        const long long ncl = (n < n_nodes) ? n : (long long)(n_nodes - 1);

        const float4 fv = *(const float4*)(f + ncl * Q + qi);

        float s = fv.x + fv.y + fv.z + fv.w;
        s += __shfl_xor(s, 1, 64);
        s += __shfl_xor(s, 2, 64);
        s += __shfl_xor(s, 4, 64);
        s += __shfl_xor(s, 8, 64);
        const float rho = s * (1.0f / 64.0f);

        const float la = lds[local];
        const float mu = lds[NPB + local];
        const float it = lds[2 * NPB + local];

        const float x0 = (float)qi * XI_H;
        float4 o;
        o.x = (rho * __expf(fmaf(la, x0,              mu)) - fv.x) * it;
        o.y = (rho * __expf(fmaf(la, x0 +        XI_H, mu)) - fv.y) * it;
        o.z = (rho * __expf(fmaf(la, x0 + 2.0f * XI_H, mu)) - fv.z) * it;
        o.w = (rho * __expf(fmaf(la, x0 + 3.0f * XI_H, mu)) - fv.w) * it;

        if (n < n_nodes) *(float4*)(out + n * Q + qi) = o;
    }
}

extern "C" void kernel_launch(void* const* d_in, const int* in_sizes, int n_in,
                              void* d_out, int out_size, void* d_ws, size_t ws_size,
                              hipStream_t stream) {
    const float* f     = (const float*)d_in[0];
    const float* macro = (const float*)d_in[1];
    const float* pos   = (const float*)d_in[2];
    const float* W0 = (const float*)d_in[3];  const float* b0 = (const float*)d_in[4];
    const float* W1 = (const float*)d_in[5];  const float* b1 = (const float*)d_in[6];
    const float* W2 = (const float*)d_in[7];  const float* b2 = (const float*)d_in[8];
    const float* W3 = (const float*)d_in[9];  const float* b3 = (const float*)d_in[10];
    const float* W4 = (const float*)d_in[11]; const float* b4 = (const float*)d_in[12];
    float* out = (float*)d_out;
    float* Wt  = (float*)d_ws;   // 3 * 64*64 floats = 48 KiB

    const int n_nodes = in_sizes[0] / Q;   // 500000
    transpose_w<<<48, 256, 0, stream>>>(W1, W2, W3, Wt);

    const int blocks = (n_nodes + NPB - 1) / NPB;
    bgk_fused<<<blocks, NPB, 0, stream>>>(f, macro, pos,
                                          W0, b0, b1, b2, b3, W4, b4, Wt,
                                          out, n_nodes);
}

// Round 3
// 157.551 us; speedup vs baseline: 2.7620x; 2.0146x over previous
//
#include <hip/hip_runtime.h>
#include <math.h>

#define Q 64
#define NPB 256
#define XS 68   // LDS activation row stride in words (64 + 4 pad for bank spread)

typedef __attribute__((ext_vector_type(8))) short bf16x8;
typedef __attribute__((ext_vector_type(4))) float f32x4;
typedef __attribute__((ext_vector_type(4))) unsigned int u32x4;

union FragU { u32x4 u; bf16x8 v; unsigned short s[8]; };

#define MFMA(a, b, cc) __builtin_amdgcn_mfma_f32_16x16x32_bf16(a, b, cc, 0, 0, 0)

__device__ __forceinline__ float fast_tanh(float x) {
    float e = __expf(2.0f * x);
    return 1.0f - __fdividef(2.0f, e + 1.0f);
}

// Split f32 into hi = bf16_rne(x) and lo = bf16_rne(x - hi): ~16 mantissa bits.
__device__ __forceinline__ void bf16split(float x, unsigned short& h, unsigned short& l) {
    unsigned u = __float_as_uint(x);
    unsigned hr = (u + 0x7fffu + ((u >> 16) & 1u)) >> 16;
    h = (unsigned short)hr;
    float rest = x - __uint_as_float(hr << 16);
    unsigned v = __float_as_uint(rest);
    l = (unsigned short)((v + 0x7fffu + ((v >> 16) & 1u)) >> 16);
}

// Pre-split weights into MFMA B-fragment order.
// ws layout (unsigned short units):
//   [0)      WBH[L][nt][kk][lane][8]   3*4*2*64*8 = 12288
//   [12288)  WBL  same
//   [24576)  L0H[nt][lane][8]          4*64*8 = 2048   (W0 rows k=0..2, bias row k=3)
//   [26624)  L0L  same
__global__ __launch_bounds__(256)
void build_wfrag(const float* __restrict__ W0, const float* __restrict__ b0,
                 const float* __restrict__ W1, const float* __restrict__ W2,
                 const float* __restrict__ W3, unsigned short* __restrict__ ws)
{
    int idx = blockIdx.x * 256 + threadIdx.x;
    if (idx < 1536) {
        int L = idx >> 9, rem = idx & 511;
        int nt = rem >> 7, kk = (rem >> 6) & 1, lane = rem & 63;
        const float* W = (L == 0) ? W1 : (L == 1) ? W2 : W3;
        int n = 16 * nt + (lane & 15);
        #pragma unroll
        for (int i = 0; i < 8; ++i) {
            int k = 8 * (lane >> 4) + 32 * kk + i;   // B[k][n] = W[n][k]
            unsigned short h, l;
            bf16split(W[n * 64 + k], h, l);
            ws[idx * 8 + i] = h;
            ws[12288 + idx * 8 + i] = l;
        }
    } else if (idx < 1792) {
        int j = idx - 1536;
        int nt = j >> 6, lane = j & 63;
        int n = 16 * nt + (lane & 15);
        #pragma unroll
        for (int i = 0; i < 8; ++i) {
            int k = 8 * (lane >> 4) + i;
            float v = (k < 3) ? W0[n * 3 + k] : ((k == 3) ? b0[n] : 0.0f);
            unsigned short h, l;
            bf16split(v, h, l);
            ws[24576 + j * 8 + i] = h;
            ws[26624 + j * 8 + i] = l;
        }
    }
}

__global__ __launch_bounds__(NPB, 2)
void bgk_mfma(const float* __restrict__ f,
              const float* __restrict__ macro,
              const float* __restrict__ pos,
              const float* __restrict__ b1,
              const float* __restrict__ b2,
              const float* __restrict__ b3,
              const float* __restrict__ W4,
              const float* __restrict__ b4,
              const unsigned short* __restrict__ ws,
              float* __restrict__ out, int n_nodes)
{
    __shared__ unsigned sX[4 * 64 * XS];          // 69632 B: per-wave 64x64 activations (hi|lo packed)
    __shared__ float s_lam[NPB], s_mu0[NPB], s_it[NPB];

    const int tid = threadIdx.x;
    const int wv = tid >> 6, lane = tid & 63;
    const int g = lane >> 4, c = lane & 15;
    const long long nbase = (long long)blockIdx.x * NPB;
    const float XI_H = 70.0f / 63.0f;

    // ---- prolog: analytic lambda/mu0 per node (thread t <-> node nbase+t) ----
    {
        long long n1 = nbase + tid;
        long long nc2 = (n1 < n_nodes) ? n1 : (long long)(n_nodes - 1);
        float m0 = macro[nc2 * 2];
        float r = fmaxf(m0 / (m0 + XI_H), 1e-30f);
        float lr = logf(r);
        s_lam[tid] = lr / XI_H;
        float r64 = __expf(64.0f * lr);
        s_mu0[tid] = -logf((1.0f - r64) / (1.0f - r));
    }

    unsigned* X = sX + wv * (64 * XS);
    const bf16x8* wbh = (const bf16x8*)(ws);
    const bf16x8* wbl = (const bf16x8*)(ws + 12288);
    const bf16x8* l0h = (const bf16x8*)(ws + 24576);
    const bf16x8* l0l = (const bf16x8*)(ws + 26624);

    const f32x4 zero4 = {0.f, 0.f, 0.f, 0.f};
    f32x4 acc[4][4];
    #pragma unroll
    for (int mt = 0; mt < 4; ++mt)
        #pragma unroll
        for (int nt = 0; nt < 4; ++nt) acc[mt][nt] = zero4;

    // ---- layer 0 (3->64) as K=32 MFMA: A = [m0,m1,pp,1,0...], B = [W0^T; b0; 0] ----
    bf16x8 a0h[4], a0l[4];
    #pragma unroll
    for (int mt = 0; mt < 4; ++mt) {
        FragU th, tl;
        th.u = (u32x4){0, 0, 0, 0};
        tl.u = (u32x4){0, 0, 0, 0};
        if (g == 0) {   // only k-group 0 carries data (k=0..3)
            long long node = nbase + (wv << 6) + 16 * mt + c;
            if (node >= n_nodes) node = n_nodes - 1;
            float m0 = macro[node * 2], m1 = macro[node * 2 + 1], pp = pos[node];
            unsigned short h, l;
            bf16split(m0, h, l); th.s[0] = h; tl.s[0] = l;
            bf16split(m1, h, l); th.s[1] = h; tl.s[1] = l;
            bf16split(pp, h, l); th.s[2] = h; tl.s[2] = l;
            th.s[3] = 0x3F80;   // 1.0 (bias column)
        }
        a0h[mt] = th.v; a0l[mt] = tl.v;
    }
    #pragma unroll
    for (int nt = 0; nt < 4; ++nt) {
        bf16x8 bh = l0h[nt * 64 + lane];
        bf16x8 bl_ = l0l[nt * 64 + lane];
        #pragma unroll
        for (int mt = 0; mt < 4; ++mt) {
            acc[mt][nt] = MFMA(a0h[mt], bh, acc[mt][nt]);
            acc[mt][nt] = MFMA(a0h[mt], bl_, acc[mt][nt]);
            acc[mt][nt] = MFMA(a0l[mt], bh, acc[mt][nt]);
        }
    }
    #pragma unroll
    for (int mt = 0; mt < 4; ++mt)
        #pragma unroll
        for (int nt = 0; nt < 4; ++nt)
            #pragma unroll
            for (int r = 0; r < 4; ++r) {
                float t = fast_tanh(acc[mt][nt][r]);
                unsigned short h, l; bf16split(t, h, l);
                X[(16 * mt + 4 * g + r) * XS + 16 * nt + c] = (unsigned)h | ((unsigned)l << 16);
            }

    // ---- hidden layers 1..3 (64->64), layer 3 feeds the 64->1 head ----
    for (int L = 0; L < 3; ++L) {
        bf16x8 ah[4][2], al[4][2];
        #pragma unroll
        for (int mt = 0; mt < 4; ++mt)
            #pragma unroll
            for (int kk = 0; kk < 2; ++kk) {
                const u32x4* p = (const u32x4*)(X + (16 * mt + c) * XS + 8 * g + 32 * kk);
                u32x4 ua = p[0], ub = p[1];
                FragU fh, fl;
                fh.u = (u32x4){ (ua.x & 0xffffu) | (ua.y << 16),
                                (ua.z & 0xffffu) | (ua.w << 16),
                                (ub.x & 0xffffu) | (ub.y << 16),
                                (ub.z & 0xffffu) | (ub.w << 16) };
                fl.u = (u32x4){ (ua.x >> 16) | (ua.y & 0xffff0000u),
                                (ua.z >> 16) | (ua.w & 0xffff0000u),
                                (ub.x >> 16) | (ub.y & 0xffff0000u),
                                (ub.z >> 16) | (ub.w & 0xffff0000u) };
                ah[mt][kk] = fh.v; al[mt][kk] = fl.v;
            }

        f32x4 nacc[4][4];
        #pragma unroll
        for (int mt = 0; mt < 4; ++mt)
            #pragma unroll
            for (int nt = 0; nt < 4; ++nt) nacc[mt][nt] = zero4;

        const bf16x8* WH = wbh + L * 512;
        const bf16x8* WL = wbl + L * 512;
        #pragma unroll
        for (int nt = 0; nt < 4; ++nt) {
            bf16x8 bh0 = WH[(nt * 2 + 0) * 64 + lane];
            bf16x8 bh1 = WH[(nt * 2 + 1) * 64 + lane];
            bf16x8 bl0 = WL[(nt * 2 + 0) * 64 + lane];
            bf16x8 bl1 = WL[(nt * 2 + 1) * 64 + lane];
            #pragma unroll
            for (int mt = 0; mt < 4; ++mt) {
                f32x4 a = nacc[mt][nt];
                a = MFMA(ah[mt][0], bh0, a);
                a = MFMA(ah[mt][0], bl0, a);
                a = MFMA(al[mt][0], bh0, a);
                a = MFMA(ah[mt][1], bh1, a);
                a = MFMA(ah[mt][1], bl1, a);
                a = MFMA(al[mt][1], bh1, a);
                nacc[mt][nt] = a;
            }
        }

        const float* bias = (L == 0) ? b1 : (L == 1) ? b2 : b3;
        float bn[4];
        #pragma unroll
        for (int nt = 0; nt < 4; ++nt) bn[nt] = bias[16 * nt + c];

        if (L < 2) {
            #pragma unroll
            for (int mt = 0; mt < 4; ++mt)
                #pragma unroll
                for (int nt = 0; nt < 4; ++nt)
                    #pragma unroll
                    for (int r = 0; r < 4; ++r) {
                        float t = fast_tanh(nacc[mt][nt][r] + bn[nt]);
                        unsigned short h, l; bf16split(t, h, l);
                        X[(16 * mt + 4 * g + r) * XS + 16 * nt + c] = (unsigned)h | ((unsigned)l << 16);
                    }
        } else {
            // head: z = b4 + sum_col W4[col]*tanh(...); row = 16mt+4g+r lives across c-lanes
            const float b4s = b4[0];
            float w4c[4];
            #pragma unroll
            for (int nt = 0; nt < 4; ++nt) w4c[nt] = W4[16 * nt + c];
            #pragma unroll
            for (int mt = 0; mt < 4; ++mt)
                #pragma unroll
                for (int r = 0; r < 4; ++r) {
                    float zp = 0.f;
                    #pragma unroll
                    for (int nt = 0; nt < 4; ++nt)
                        zp = fmaf(w4c[nt], fast_tanh(nacc[mt][nt][r] + bn[nt]), zp);
                    zp += __shfl_xor(zp, 1, 64);
                    zp += __shfl_xor(zp, 2, 64);
                    zp += __shfl_xor(zp, 4, 64);
                    zp += __shfl_xor(zp, 8, 64);
                    float it = __expf(-(zp + b4s));
                    if (c == 0) s_it[(wv << 6) + 16 * mt + 4 * g + r] = it;
                }
        }
    }
    __syncthreads();

    // ---- Phase 2: streaming omega, 4 nodes per wave-iter (float4) ----
    const int sub = lane >> 4;
    const int qi = (lane & 15) * 4;
    for (int k = 0; k < 16; ++k) {
        const int local = (wv << 6) + k * 4 + sub;
        const long long n = nbase + local;
        const long long ncl = (n < n_nodes) ? n : (long long)(n_nodes - 1);

        const float4 fv = *(const float4*)(f + ncl * Q + qi);
        float s = fv.x + fv.y + fv.z + fv.w;
        s += __shfl_xor(s, 1, 64);
        s += __shfl_xor(s, 2, 64);
        s += __shfl_xor(s, 4, 64);
        s += __shfl_xor(s, 8, 64);
        const float rho = s * (1.0f / 64.0f);

        const float la = s_lam[local];
        const float mu = s_mu0[local];
        const float it = s_it[local];

        const float x0 = (float)qi * XI_H;
        float4 o;
        o.x = (rho * __expf(fmaf(la, x0,               mu)) - fv.x) * it;
        o.y = (rho * __expf(fmaf(la, x0 +        XI_H, mu)) - fv.y) * it;
        o.z = (rho * __expf(fmaf(la, x0 + 2.0f * XI_H, mu)) - fv.z) * it;
        o.w = (rho * __expf(fmaf(la, x0 + 3.0f * XI_H, mu)) - fv.w) * it;

        if (n < n_nodes) *(float4*)(out + n * Q + qi) = o;
    }
}

extern "C" void kernel_launch(void* const* d_in, const int* in_sizes, int n_in,
                              void* d_out, int out_size, void* d_ws, size_t ws_size,
                              hipStream_t stream) {
    const float* f     = (const float*)d_in[0];
    const float* macro = (const float*)d_in[1];
    const float* pos   = (const float*)d_in[2];
    const float* W0 = (const float*)d_in[3];  const float* b0 = (const float*)d_in[4];
    const float* W1 = (const float*)d_in[5];  const float* b1 = (const float*)d_in[6];
    const float* W2 = (const float*)d_in[7];  const float* b2 = (const float*)d_in[8];
    const float* W3 = (const float*)d_in[9];  const float* b3 = (const float*)d_in[10];
    const float* W4 = (const float*)d_in[11]; const float* b4 = (const float*)d_in[12];
    float* out = (float*)d_out;
    unsigned short* ws = (unsigned short*)d_ws;   // 57344 B used

    const int n_nodes = in_sizes[0] / Q;   // 500000
    build_wfrag<<<7, 256, 0, stream>>>(W0, b0, W1, W2, W3, ws);

    const int blocks = (n_nodes + NPB - 1) / NPB;
    bgk_mfma<<<blocks, NPB, 0, stream>>>(f, macro, pos,
                                         b1, b2, b3, W4, b4, ws,
                                         out, n_nodes);
}

// Round 4
// 114.668 us; speedup vs baseline: 3.7950x; 1.3740x over previous
//
#include <hip/hip_runtime.h>
#include <math.h>

#define Q 64
#define NPB 256
#define XS 72   // LDS activation row stride in bf16 elements (64 + 8 pad; keeps 16B alignment)

typedef __attribute__((ext_vector_type(8))) short bf16x8;
typedef __attribute__((ext_vector_type(4))) float f32x4;
typedef __attribute__((ext_vector_type(4))) unsigned int u32x4;

union FragU { u32x4 u; bf16x8 v; unsigned short s[8]; };

#define MFMA(a, b, cc) __builtin_amdgcn_mfma_f32_16x16x32_bf16(a, b, cc, 0, 0, 0)

__device__ __forceinline__ float fast_tanh(float x) {
    float e = __expf(2.0f * x);
    return 1.0f - __fdividef(2.0f, e + 1.0f);
}

__device__ __forceinline__ unsigned short bf16rne(float x) {
    unsigned u = __float_as_uint(x);
    return (unsigned short)((u + 0x7fffu + ((u >> 16) & 1u)) >> 16);
}

__device__ __forceinline__ void bf16split(float x, unsigned short& h, unsigned short& l) {
    h = bf16rne(x);
    float rest = x - __uint_as_float(((unsigned)h) << 16);
    l = bf16rne(rest);
}

// Pre-split weights into MFMA B-fragment order (hi + lo planes).
// ws layout (unsigned short units):
//   [0)      WBH[L][nt][kk][lane][8]   3*4*2*64*8 = 12288
//   [12288)  WBL  same
//   [24576)  L0H[nt][lane][8]          4*64*8 = 2048   (W0 rows k=0..2, bias row k=3)
//   [26624)  L0L  same
__global__ __launch_bounds__(256)
void build_wfrag(const float* __restrict__ W0, const float* __restrict__ b0,
                 const float* __restrict__ W1, const float* __restrict__ W2,
                 const float* __restrict__ W3, unsigned short* __restrict__ ws)
{
    int idx = blockIdx.x * 256 + threadIdx.x;
    if (idx < 1536) {
        int L = idx >> 9, rem = idx & 511;
        int nt = rem >> 7, kk = (rem >> 6) & 1, lane = rem & 63;
        const float* W = (L == 0) ? W1 : (L == 1) ? W2 : W3;
        int n = 16 * nt + (lane & 15);
        #pragma unroll
        for (int i = 0; i < 8; ++i) {
            int k = 8 * (lane >> 4) + 32 * kk + i;   // B[k][n] = W[n][k]
            unsigned short h, l;
            bf16split(W[n * 64 + k], h, l);
            ws[idx * 8 + i] = h;
            ws[12288 + idx * 8 + i] = l;
        }
    } else if (idx < 1792) {
        int j = idx - 1536;
        int nt = j >> 6, lane = j & 63;
        int n = 16 * nt + (lane & 15);
        #pragma unroll
        for (int i = 0; i < 8; ++i) {
            int k = 8 * (lane >> 4) + i;
            float v = (k < 3) ? W0[n * 3 + k] : ((k == 3) ? b0[n] : 0.0f);
            unsigned short h, l;
            bf16split(v, h, l);
            ws[24576 + j * 8 + i] = h;
            ws[26624 + j * 8 + i] = l;
        }
    }
}

__global__ __launch_bounds__(NPB, 4)
void bgk_mfma(const float* __restrict__ f,
              const float* __restrict__ macro,
              const float* __restrict__ pos,
              const float* __restrict__ b1,
              const float* __restrict__ b2,
              const float* __restrict__ b3,
              const float* __restrict__ W4,
              const float* __restrict__ b4,
              const unsigned short* __restrict__ ws,
              float* __restrict__ out, int n_nodes)
{
    // Per-wave 64x64 bf16 activation tile, row stride XS (rows 16B-aligned).
    __shared__ unsigned short sXs[4 * 64 * XS];          // 36,864 B
    __shared__ float s_lam[NPB], s_mu0[NPB], s_it[NPB];  // 3,072 B

    const int tid = threadIdx.x;
    const int wv = tid >> 6, lane = tid & 63;
    const int g = lane >> 4, c = lane & 15;
    const long long nbase = (long long)blockIdx.x * NPB;
    const float XI_H = 70.0f / 63.0f;

    // ---- prolog: analytic lambda/mu0 per node (geometric fixed point of Newton) ----
    {
        long long n1 = nbase + tid;
        long long nc2 = (n1 < n_nodes) ? n1 : (long long)(n_nodes - 1);
        float m0 = macro[nc2 * 2];
        float r = fmaxf(m0 / (m0 + XI_H), 1e-30f);
        float lr = logf(r);
        s_lam[tid] = lr / XI_H;
        float r64 = __expf(64.0f * lr);
        s_mu0[tid] = -logf((1.0f - r64) / (1.0f - r));
    }

    unsigned short* X = sXs + wv * 64 * XS;
    const bf16x8* wbh = (const bf16x8*)(ws);
    const bf16x8* wbl = (const bf16x8*)(ws + 12288);
    const bf16x8* l0h = (const bf16x8*)(ws + 24576);
    const bf16x8* l0l = (const bf16x8*)(ws + 26624);

    const f32x4 zero4 = {0.f, 0.f, 0.f, 0.f};

    // ---- layer 0 (3->64), K=32 MFMA, bias folded as A-column of 1.0 ----
    {
        bf16x8 a0h[4], a0l[4];
        #pragma unroll
        for (int mt = 0; mt < 4; ++mt) {
            FragU th, tl;
            th.u = (u32x4){0, 0, 0, 0};
            tl.u = (u32x4){0, 0, 0, 0};
            if (g == 0) {   // only k-group 0 carries data (k=0..3)
                long long node = nbase + (wv << 6) + 16 * mt + c;
                if (node >= n_nodes) node = n_nodes - 1;
                float m0 = macro[node * 2], m1 = macro[node * 2 + 1], pp = pos[node];
                unsigned short h, l;
                bf16split(m0, h, l); th.s[0] = h; tl.s[0] = l;
                bf16split(m1, h, l); th.s[1] = h; tl.s[1] = l;
                bf16split(pp, h, l); th.s[2] = h; tl.s[2] = l;
                th.s[3] = 0x3F80;   // 1.0 (bias column)
            }
            a0h[mt] = th.v; a0l[mt] = tl.v;
        }
        #pragma unroll
        for (int nt = 0; nt < 4; ++nt) {
            bf16x8 bh = l0h[nt * 64 + lane];
            bf16x8 bl_ = l0l[nt * 64 + lane];
            #pragma unroll
            for (int mt = 0; mt < 4; ++mt) {
                f32x4 t = zero4;
                t = MFMA(a0h[mt], bh, t);
                t = MFMA(a0h[mt], bl_, t);
                t = MFMA(a0l[mt], bh, t);
                #pragma unroll
                for (int r = 0; r < 4; ++r)
                    X[(16 * mt + 4 * g + r) * XS + 16 * nt + c] = bf16rne(fast_tanh(t[r]));
            }
        }
    }

    // ---- hidden layers 1,2 (64->64): bf16 activations x (Wh + Wl) ----
    #pragma unroll 1
    for (int L = 0; L < 2; ++L) {
        f32x4 acc[4][4];
        #pragma unroll
        for (int mt = 0; mt < 4; ++mt)
            #pragma unroll
            for (int nt = 0; nt < 4; ++nt) acc[mt][nt] = zero4;

        const bf16x8* WH = wbh + L * 512;
        const bf16x8* WL = wbl + L * 512;
        #pragma unroll
        for (int nt = 0; nt < 4; ++nt) {
            bf16x8 bh0 = WH[(nt * 2 + 0) * 64 + lane];
            bf16x8 bh1 = WH[(nt * 2 + 1) * 64 + lane];
            bf16x8 bl0 = WL[(nt * 2 + 0) * 64 + lane];
            bf16x8 bl1 = WL[(nt * 2 + 1) * 64 + lane];
            #pragma unroll
            for (int mt = 0; mt < 4; ++mt) {
                bf16x8 a0 = *(const bf16x8*)&X[(16 * mt + c) * XS + 8 * g];
                bf16x8 a1 = *(const bf16x8*)&X[(16 * mt + c) * XS + 8 * g + 32];
                f32x4 t = acc[mt][nt];
                t = MFMA(a0, bh0, t);
                t = MFMA(a0, bl0, t);
                t = MFMA(a1, bh1, t);
                t = MFMA(a1, bl1, t);
                acc[mt][nt] = t;
            }
        }
        const float* bias = (L == 0) ? b1 : b2;
        float bn[4];
        #pragma unroll
        for (int nt = 0; nt < 4; ++nt) bn[nt] = bias[16 * nt + c];
        // all X reads for this layer are complete; in-place overwrite is safe (wave-private)
        #pragma unroll
        for (int mt = 0; mt < 4; ++mt)
            #pragma unroll
            for (int nt = 0; nt < 4; ++nt)
                #pragma unroll
                for (int r = 0; r < 4; ++r)
                    X[(16 * mt + 4 * g + r) * XS + 16 * nt + c] =
                        bf16rne(fast_tanh(acc[mt][nt][r] + bn[nt]));
    }

    // ---- hidden layer 3 + head (64->64->1), no X writeback ----
    {
        const bf16x8* WH = wbh + 2 * 512;
        const bf16x8* WL = wbl + 2 * 512;
        float zp[4][4];   // [mt][r] partial head sums
        #pragma unroll
        for (int mt = 0; mt < 4; ++mt)
            #pragma unroll
            for (int r = 0; r < 4; ++r) zp[mt][r] = 0.f;

        #pragma unroll
        for (int nt = 0; nt < 4; ++nt) {
            bf16x8 bh0 = WH[(nt * 2 + 0) * 64 + lane];
            bf16x8 bh1 = WH[(nt * 2 + 1) * 64 + lane];
            bf16x8 bl0 = WL[(nt * 2 + 0) * 64 + lane];
            bf16x8 bl1 = WL[(nt * 2 + 1) * 64 + lane];
            const float bn = b3[16 * nt + c];
            const float w4 = W4[16 * nt + c];
            #pragma unroll
            for (int mt = 0; mt < 4; ++mt) {
                bf16x8 a0 = *(const bf16x8*)&X[(16 * mt + c) * XS + 8 * g];
                bf16x8 a1 = *(const bf16x8*)&X[(16 * mt + c) * XS + 8 * g + 32];
                f32x4 t = zero4;
                t = MFMA(a0, bh0, t);
                t = MFMA(a0, bl0, t);
                t = MFMA(a1, bh1, t);
                t = MFMA(a1, bl1, t);
                #pragma unroll
                for (int r = 0; r < 4; ++r)
                    zp[mt][r] = fmaf(w4, fast_tanh(t[r] + bn), zp[mt][r]);
            }
        }
        const float b4s = b4[0];
        #pragma unroll
        for (int mt = 0; mt < 4; ++mt)
            #pragma unroll
            for (int r = 0; r < 4; ++r) {
                float z = zp[mt][r];
                z += __shfl_xor(z, 1, 64);
                z += __shfl_xor(z, 2, 64);
                z += __shfl_xor(z, 4, 64);
                z += __shfl_xor(z, 8, 64);
                if (c == 0)
                    s_it[(wv << 6) + 16 * mt + 4 * g + r] = __expf(-(z + b4s));
            }
    }
    __syncthreads();

    // ---- Phase 2: streaming omega, 4 nodes per wave-iter (float4) ----
    const int sub = lane >> 4;
    const int qi = (lane & 15) * 4;
    for (int k = 0; k < 16; ++k) {
        const int local = (wv << 6) + k * 4 + sub;
        const long long n = nbase + local;
        const long long ncl = (n < n_nodes) ? n : (long long)(n_nodes - 1);

        const float4 fv = *(const float4*)(f + ncl * Q + qi);
        float s = fv.x + fv.y + fv.z + fv.w;
        s += __shfl_xor(s, 1, 64);
        s += __shfl_xor(s, 2, 64);
        s += __shfl_xor(s, 4, 64);
        s += __shfl_xor(s, 8, 64);
        const float rho = s * (1.0f / 64.0f);

        const float la = s_lam[local];
        const float mu = s_mu0[local];
        const float it = s_it[local];

        const float x0 = (float)qi * XI_H;
        float4 o;
        o.x = (rho * __expf(fmaf(la, x0,               mu)) - fv.x) * it;
        o.y = (rho * __expf(fmaf(la, x0 +        XI_H, mu)) - fv.y) * it;
        o.z = (rho * __expf(fmaf(la, x0 + 2.0f * XI_H, mu)) - fv.z) * it;
        o.w = (rho * __expf(fmaf(la, x0 + 3.0f * XI_H, mu)) - fv.w) * it;

        if (n < n_nodes) *(float4*)(out + n * Q + qi) = o;
    }
}

extern "C" void kernel_launch(void* const* d_in, const int* in_sizes, int n_in,
                              void* d_out, int out_size, void* d_ws, size_t ws_size,
                              hipStream_t stream) {
    const float* f     = (const float*)d_in[0];
    const float* macro = (const float*)d_in[1];
    const float* pos   = (const float*)d_in[2];
    const float* W0 = (const float*)d_in[3];  const float* b0 = (const float*)d_in[4];
    const float* W1 = (const float*)d_in[5];  const float* b1 = (const float*)d_in[6];
    const float* W2 = (const float*)d_in[7];  const float* b2 = (const float*)d_in[8];
    const float* W3 = (const float*)d_in[9];  const float* b3 = (const float*)d_in[10];
    const float* W4 = (const float*)d_in[11]; const float* b4 = (const float*)d_in[12];
    float* out = (float*)d_out;
    unsigned short* ws = (unsigned short*)d_ws;   // 57,344 B used

    const int n_nodes = in_sizes[0] / Q;   // 500000
    build_wfrag<<<7, 256, 0, stream>>>(W0, b0, W1, W2, W3, ws);

    const int blocks = (n_nodes + NPB - 1) / NPB;
    bgk_mfma<<<blocks, NPB, 0, stream>>>(f, macro, pos,
                                         b1, b2, b3, W4, b4, ws,
                                         out, n_nodes);
}

// Round 5
// 114.188 us; speedup vs baseline: 3.8109x; 1.0042x over previous
//
#include <hip/hip_runtime.h>
#include <math.h>

#define Q 64
#define NPB 256
#define XS 72   // LDS activation row stride in bf16 elements (rows 144 B, 16B-aligned)

typedef __attribute__((ext_vector_type(8))) short bf16x8;
typedef __attribute__((ext_vector_type(4))) float f32x4;
typedef __attribute__((ext_vector_type(4))) unsigned int u32x4;

union FragU { u32x4 u; bf16x8 v; unsigned short s[8]; };

#define MFMA(a, b, cc) __builtin_amdgcn_mfma_f32_16x16x32_bf16(a, b, cc, 0, 0, 0)

__device__ __forceinline__ float fast_tanh(float x) {
    float e = __expf(2.0f * x);
    return 1.0f - __fdividef(2.0f, e + 1.0f);
}

__device__ __forceinline__ unsigned short bf16rne(float x) {
    unsigned u = __float_as_uint(x);
    return (unsigned short)((u + 0x7fffu + ((u >> 16) & 1u)) >> 16);
}

__device__ __forceinline__ void bf16split(float x, unsigned short& h, unsigned short& l) {
    h = bf16rne(x);
    float rest = x - __uint_as_float(((unsigned)h) << 16);
    l = bf16rne(rest);
}

// Packed f32->bf16 RNE conversion: dst = {bf16(lo) in [15:0], bf16(hi) in [31:16]}
__device__ __forceinline__ unsigned cvt_pk_bf16(float lo, float hi) {
    unsigned r;
    asm("v_cvt_pk_bf16_f32 %0, %1, %2" : "=v"(r) : "v"(lo), "v"(hi));
    return r;
}

// Pre-split weights into MFMA A-fragment order (hi + lo planes).
// ws layout (unsigned short units):
//   [0)      WAH[L][mt][kk][lane][8]   3*4*2*64*8 = 12288   (W1,W2,W3 as A: row=out-feat)
//   [12288)  WAL  same
//   [24576)  L0H[mt][lane][8]          4*64*8 = 2048        (W0 cols k=0..2, bias col k=3)
//   [26624)  L0L  same
__global__ __launch_bounds__(256)
void build_wfrag(const float* __restrict__ W0, const float* __restrict__ b0,
                 const float* __restrict__ W1, const float* __restrict__ W2,
                 const float* __restrict__ W3, unsigned short* __restrict__ ws)
{
    int idx = blockIdx.x * 256 + threadIdx.x;
    if (idx < 1536) {
        int L = idx >> 9, rem = idx & 511;
        int mt = rem >> 7, kk = (rem >> 6) & 1, lane = rem & 63;
        const float* W = (L == 0) ? W1 : (L == 1) ? W2 : W3;
        int n = 16 * mt + (lane & 15);            // out-feat row
        #pragma unroll
        for (int i = 0; i < 8; ++i) {
            int k = 8 * (lane >> 4) + 32 * kk + i; // in-feat col
            unsigned short h, l;
            bf16split(W[n * 64 + k], h, l);
            ws[idx * 8 + i] = h;
            ws[12288 + idx * 8 + i] = l;
        }
    } else if (idx < 1792) {
        int j = idx - 1536;
        int mt = j >> 6, lane = j & 63;
        int n = 16 * mt + (lane & 15);
        #pragma unroll
        for (int i = 0; i < 8; ++i) {
            int k = 8 * (lane >> 4) + i;
            float v = (k < 3) ? W0[n * 3 + k] : ((k == 3) ? b0[n] : 0.0f);
            unsigned short h, l;
            bf16split(v, h, l);
            ws[24576 + j * 8 + i] = h;
            ws[26624 + j * 8 + i] = l;
        }
    }
}

__global__ __launch_bounds__(NPB, 4)
void bgk_mfma(const float* __restrict__ f,
              const float* __restrict__ macro,
              const float* __restrict__ pos,
              const float* __restrict__ b1,
              const float* __restrict__ b2,
              const float* __restrict__ b3,
              const float* __restrict__ W4,
              const float* __restrict__ b4,
              const unsigned short* __restrict__ ws,
              float* __restrict__ out, int n_nodes)
{
    // Per-wave activation tile X[node][feat], 64 nodes x XS bf16.
    __shared__ unsigned short sXs[4 * 64 * XS];   // 36,864 B
    __shared__ float s_it[NPB];                   //  1,024 B

    const int tid = threadIdx.x;
    const int wv = tid >> 6, lane = tid & 63;
    const int g = lane >> 4, c = lane & 15;
    const long long nbase = (long long)blockIdx.x * NPB;
    const float XI_H = 70.0f / 63.0f;

    // ---- prolog: analytic lambda/mu0/r per node (thread t <-> node nbase+t) ----
    float lam, mu0, rgeo;
    {
        long long n1 = nbase + tid;
        long long nc2 = (n1 < n_nodes) ? n1 : (long long)(n_nodes - 1);
        float m0 = macro[nc2 * 2];
        rgeo = fmaxf(m0 / (m0 + XI_H), 1e-30f);
        float lr = logf(rgeo);
        lam = lr / XI_H;
        float r64 = __expf(64.0f * lr);
        mu0 = -logf((1.0f - r64) / (1.0f - rgeo));
    }

    unsigned short* X = sXs + wv * 64 * XS;
    const bf16x8* wAh = (const bf16x8*)(ws);
    const bf16x8* wAl = (const bf16x8*)(ws + 12288);
    const bf16x8* l0h = (const bf16x8*)(ws + 24576);
    const bf16x8* l0l = (const bf16x8*)(ws + 26624);
    const f32x4 zero4 = {0.f, 0.f, 0.f, 0.f};

    // ---- layer 0 (3->64), D = W0ext * X0, K=32, bias folded as input row of 1.0 ----
    {
        bf16x8 B0h[4], B0l[4];
        #pragma unroll
        for (int nt = 0; nt < 4; ++nt) {
            FragU th, tl;
            th.u = (u32x4){0, 0, 0, 0};
            tl.u = (u32x4){0, 0, 0, 0};
            if (g == 0) {   // only k=0..3 carry data
                long long node = nbase + (wv << 6) + 16 * nt + c;
                if (node >= n_nodes) node = n_nodes - 1;
                float m0 = macro[node * 2], m1 = macro[node * 2 + 1], pp = pos[node];
                unsigned short h, l;
                bf16split(m0, h, l); th.s[0] = h; tl.s[0] = l;
                bf16split(m1, h, l); th.s[1] = h; tl.s[1] = l;
                bf16split(pp, h, l); th.s[2] = h; tl.s[2] = l;
                th.s[3] = 0x3F80;   // 1.0 (bias row)
            }
            B0h[nt] = th.v; B0l[nt] = tl.v;
        }
        #pragma unroll
        for (int mt = 0; mt < 4; ++mt) {
            bf16x8 Ah = l0h[mt * 64 + lane];
            bf16x8 Al = l0l[mt * 64 + lane];
            #pragma unroll
            for (int nt = 0; nt < 4; ++nt) {
                f32x4 t = zero4;
                t = MFMA(Ah, B0h[nt], t);
                t = MFMA(Al, B0h[nt], t);
                t = MFMA(Ah, B0l[nt], t);
                float t0 = fast_tanh(t[0]);
                float t1 = fast_tanh(t[1]);
                float t2 = fast_tanh(t[2]);
                float t3 = fast_tanh(t[3]);
                uint2 pk = { cvt_pk_bf16(t0, t1), cvt_pk_bf16(t2, t3) };
                *(uint2*)&X[(16 * nt + c) * XS + 16 * mt + 4 * g] = pk;
            }
        }
    }

    // ---- hidden layers 1,2 (64->64): D = W * X, activations bf16, weights hi+lo ----
    #pragma unroll 1
    for (int L = 0; L < 2; ++L) {
        const float* bias = (L == 0) ? b1 : b2;
        // read ALL B-fragments first (wave-synchronous: safe vs in-place overwrite)
        bf16x8 Bf0[4], Bf1[4];
        #pragma unroll
        for (int nt = 0; nt < 4; ++nt) {
            Bf0[nt] = *(const bf16x8*)&X[(16 * nt + c) * XS + 8 * g];
            Bf1[nt] = *(const bf16x8*)&X[(16 * nt + c) * XS + 8 * g + 32];
        }
        #pragma unroll
        for (int mt = 0; mt < 4; ++mt) {
            const int fo = ((L * 4 + mt) * 2) * 64 + lane;
            bf16x8 Ah0 = wAh[fo], Ah1 = wAh[fo + 64];
            bf16x8 Al0 = wAl[fo], Al1 = wAl[fo + 64];
            float4 bv = *(const float4*)&bias[16 * mt + 4 * g];
            #pragma unroll
            for (int nt = 0; nt < 4; ++nt) {
                f32x4 t = zero4;
                t = MFMA(Ah0, Bf0[nt], t);
                t = MFMA(Al0, Bf0[nt], t);
                t = MFMA(Ah1, Bf1[nt], t);
                t = MFMA(Al1, Bf1[nt], t);
                float t0 = fast_tanh(t[0] + bv.x);
                float t1 = fast_tanh(t[1] + bv.y);
                float t2 = fast_tanh(t[2] + bv.z);
                float t3 = fast_tanh(t[3] + bv.w);
                uint2 pk = { cvt_pk_bf16(t0, t1), cvt_pk_bf16(t2, t3) };
                *(uint2*)&X[(16 * nt + c) * XS + 16 * mt + 4 * g] = pk;
            }
        }
    }

    // ---- layer 3 + head (64->64->1): no writeback, fold W4 ----
    {
        bf16x8 Bf0[4], Bf1[4];
        #pragma unroll
        for (int nt = 0; nt < 4; ++nt) {
            Bf0[nt] = *(const bf16x8*)&X[(16 * nt + c) * XS + 8 * g];
            Bf1[nt] = *(const bf16x8*)&X[(16 * nt + c) * XS + 8 * g + 32];
        }
        float zp[4] = {0.f, 0.f, 0.f, 0.f};
        #pragma unroll
        for (int mt = 0; mt < 4; ++mt) {
            const int fo = ((2 * 4 + mt) * 2) * 64 + lane;
            bf16x8 Ah0 = wAh[fo], Ah1 = wAh[fo + 64];
            bf16x8 Al0 = wAl[fo], Al1 = wAl[fo + 64];
            float4 bv = *(const float4*)&b3[16 * mt + 4 * g];
            float4 wv4 = *(const float4*)&W4[16 * mt + 4 * g];
            #pragma unroll
            for (int nt = 0; nt < 4; ++nt) {
                f32x4 t = zero4;
                t = MFMA(Ah0, Bf0[nt], t);
                t = MFMA(Al0, Bf0[nt], t);
                t = MFMA(Ah1, Bf1[nt], t);
                t = MFMA(Al1, Bf1[nt], t);
                float z = zp[nt];
                z = fmaf(wv4.x, fast_tanh(t[0] + bv.x), z);
                z = fmaf(wv4.y, fast_tanh(t[1] + bv.y), z);
                z = fmaf(wv4.z, fast_tanh(t[2] + bv.z), z);
                z = fmaf(wv4.w, fast_tanh(t[3] + bv.w), z);
                zp[nt] = z;
            }
        }
        const float b4s = b4[0];
        #pragma unroll
        for (int nt = 0; nt < 4; ++nt) {
            float z = zp[nt];
            z += __shfl_xor(z, 16, 64);
            z += __shfl_xor(z, 32, 64);
            if (g == 0)
                s_it[(wv << 6) + 16 * nt + c] = __expf(-(z + b4s));
        }
    }

    // ---- Phase 2: streaming omega; feq via geometric recurrence (1 exp/iter) ----
    const int sub = lane >> 4;
    const int qi = (lane & 15) * 4;
    const float x0 = (float)qi * XI_H;
    for (int k = 0; k < 16; ++k) {
        const int local = k * 4 + sub;                 // node within this wave
        const long long n = nbase + (wv << 6) + local;
        const long long ncl = (n < n_nodes) ? n : (long long)(n_nodes - 1);

        const float4 fv = *(const float4*)(f + ncl * Q + qi);
        float s = fv.x + fv.y + fv.z + fv.w;
        s += __shfl_xor(s, 1, 64);
        s += __shfl_xor(s, 2, 64);
        s += __shfl_xor(s, 4, 64);
        s += __shfl_xor(s, 8, 64);
        const float rho = s * (1.0f / 64.0f);

        const float la = __shfl(lam,  local, 64);
        const float mu = __shfl(mu0,  local, 64);
        const float rr = __shfl(rgeo, local, 64);
        const float it = s_it[(wv << 6) + local];

        const float e0 = rho * __expf(fmaf(la, x0, mu));
        const float e1 = e0 * rr;
        const float e2 = e1 * rr;
        const float e3 = e2 * rr;

        float4 o;
        o.x = (e0 - fv.x) * it;
        o.y = (e1 - fv.y) * it;
        o.z = (e2 - fv.z) * it;
        o.w = (e3 - fv.w) * it;

        if (n < n_nodes) *(float4*)(out + n * Q + qi) = o;
    }
}

extern "C" void kernel_launch(void* const* d_in, const int* in_sizes, int n_in,
                              void* d_out, int out_size, void* d_ws, size_t ws_size,
                              hipStream_t stream) {
    const float* f     = (const float*)d_in[0];
    const float* macro = (const float*)d_in[1];
    const float* pos   = (const float*)d_in[2];
    const float* W0 = (const float*)d_in[3];  const float* b0 = (const float*)d_in[4];
    const float* W1 = (const float*)d_in[5];  const float* b1 = (const float*)d_in[6];
    const float* W2 = (const float*)d_in[7];  const float* b2 = (const float*)d_in[8];
    const float* W3 = (const float*)d_in[9];  const float* b3 = (const float*)d_in[10];
    const float* W4 = (const float*)d_in[11]; const float* b4 = (const float*)d_in[12];
    float* out = (float*)d_out;
    unsigned short* ws = (unsigned short*)d_ws;   // 57,344 B used

    const int n_nodes = in_sizes[0] / Q;   // 500000
    build_wfrag<<<7, 256, 0, stream>>>(W0, b0, W1, W2, W3, ws);

    const int blocks = (n_nodes + NPB - 1) / NPB;
    bgk_mfma<<<blocks, NPB, 0, stream>>>(f, macro, pos,
                                         b1, b2, b3, W4, b4, ws,
                                         out, n_nodes);
}